// Round 1
// baseline (1099.085 us; speedup 1.0000x reference)
//
#include <hip/hip_runtime.h>
#include <math.h>

#define B_   2
#define S_   2048
#define D_   1024
#define H_   16
#define DK_  64
#define SCALE_ 0.125f
#define MASKV_ (-1.0e9f)

// ---------------------------------------------------------------------------
// GEMM: Y = X @ W^T + bias.   X [M, 1024] row-major, W [1024(out), 1024(in)]
// Tile 64x64, K-step 16. 256 threads, each computes a 4x4 micro-tile.
// LDS tiles stored K-major (transposed) so the inner loop is 2 ds_read_b128
// per 16 FMA. head_layout=1 writes Y in [B,H,S,Dk]; else plain [M,1024].
// ---------------------------------------------------------------------------
__global__ __launch_bounds__(256) void proj_kernel(
    const float* __restrict__ X, const float* __restrict__ W,
    const float* __restrict__ bias, float* __restrict__ Y, int head_layout)
{
    __shared__ float xs[16][68];
    __shared__ float ws[16][68];
    const int t  = threadIdx.x;
    const int tm = t >> 4;        // 0..15 (output row group)
    const int tn = t & 15;        // 0..15 (output col group)
    const int m0 = blockIdx.y * 64;
    const int n0 = blockIdx.x * 64;
    const int lr = t >> 2;        // staging row 0..63
    const int lc = t & 3;         // staging float4 chunk 0..3

    float acc[4][4] = {};

    for (int k0 = 0; k0 < D_; k0 += 16) {
        float4 xv = *(const float4*)&X[(size_t)(m0 + lr) * D_ + k0 + lc * 4];
        float4 wv = *(const float4*)&W[(size_t)(n0 + lr) * D_ + k0 + lc * 4];
        __syncthreads();   // previous iteration's readers are done
        xs[lc*4+0][lr] = xv.x; xs[lc*4+1][lr] = xv.y;
        xs[lc*4+2][lr] = xv.z; xs[lc*4+3][lr] = xv.w;
        ws[lc*4+0][lr] = wv.x; ws[lc*4+1][lr] = wv.y;
        ws[lc*4+2][lr] = wv.z; ws[lc*4+3][lr] = wv.w;
        __syncthreads();
        #pragma unroll
        for (int kk = 0; kk < 16; ++kk) {
            float4 a = *(const float4*)&xs[kk][tm * 4];
            float4 b = *(const float4*)&ws[kk][tn * 4];
            float av[4] = {a.x, a.y, a.z, a.w};
            float bv[4] = {b.x, b.y, b.z, b.w};
            #pragma unroll
            for (int i = 0; i < 4; ++i)
                #pragma unroll
                for (int j = 0; j < 4; ++j)
                    acc[i][j] = fmaf(av[i], bv[j], acc[i][j]);
        }
    }

    float4 b4 = *(const float4*)&bias[n0 + tn * 4];
    float bb[4] = {b4.x, b4.y, b4.z, b4.w};
    #pragma unroll
    for (int i = 0; i < 4; ++i) {
        const int m = m0 + tm * 4 + i;
        float4 o;
        o.x = acc[i][0] + bb[0];
        o.y = acc[i][1] + bb[1];
        o.z = acc[i][2] + bb[2];
        o.w = acc[i][3] + bb[3];
        if (head_layout) {
            const int bidx = m >> 11;         // m / S_
            const int s    = m & (S_ - 1);
            const int h    = n0 >> 6;         // 64-wide N tile == one head
            *(float4*)&Y[(size_t)(((bidx * H_ + h) * S_ + s)) * DK_ + tn * 4] = o;
        } else {
            *(float4*)&Y[(size_t)m * D_ + n0 + tn * 4] = o;
        }
    }
}

// ---------------------------------------------------------------------------
// Causal flash attention, fp32. One block per (q-tile of 64, head, batch).
// 256 threads; each owns a 4x4 micro-tile of the 64x64 score tile and a
// 4(rows)x4(dims) slice of O. Row softmax stats via 16-lane __shfl_xor.
// ---------------------------------------------------------------------------
__global__ __launch_bounds__(256) void attn_kernel(
    const float* __restrict__ Qg, const float* __restrict__ Kg,
    const float* __restrict__ Vg, float* __restrict__ ctx)
{
    __shared__ float qt[64][68];  // [d][m]  (Q tile, transposed)
    __shared__ float kt[64][68];  // [d][n]  (K tile, transposed)
    __shared__ float vs[64][68];  // [k][d]  (V tile, natural)
    __shared__ float pt[64][68];  // [k][m]  (P tile, transposed)

    const int t  = threadIdx.x;
    const int tm = t >> 4;                       // 0..15
    const int tn = t & 15;                       // 0..15
    const int qtile = (S_ / 64 - 1) - blockIdx.x;  // longest blocks first
    const int h = blockIdx.y, b = blockIdx.z;
    const int q0 = qtile * 64;

    const float* Qb = Qg + (size_t)((b * H_ + h) * S_) * DK_;
    const float* Kb = Kg + (size_t)((b * H_ + h) * S_) * DK_;
    const float* Vb = Vg + (size_t)((b * H_ + h) * S_) * DK_;

    // stage Q tile transposed: qt[d][m]
    {
        const int r = t & 63, g = t >> 6;
        #pragma unroll
        for (int u = 0; u < 4; ++u) {
            const int d = g * 16 + u * 4;
            float4 v = *(const float4*)&Qb[(size_t)(q0 + r) * DK_ + d];
            qt[d + 0][r] = v.x; qt[d + 1][r] = v.y;
            qt[d + 2][r] = v.z; qt[d + 3][r] = v.w;
        }
    }

    float o[4][4] = {};
    float mrun[4], lrun[4];
    #pragma unroll
    for (int i = 0; i < 4; ++i) { mrun[i] = -INFINITY; lrun[i] = 0.0f; }

    for (int kb = 0; kb <= qtile; ++kb) {
        const int k0 = kb * 64;
        __syncthreads();  // previous iteration done with kt/vs/pt (also fences Q staging)
        {
            const int r = t & 63, g = t >> 6;
            #pragma unroll
            for (int u = 0; u < 4; ++u) {
                const int d = g * 16 + u * 4;
                float4 kv = *(const float4*)&Kb[(size_t)(k0 + r) * DK_ + d];
                kt[d + 0][r] = kv.x; kt[d + 1][r] = kv.y;
                kt[d + 2][r] = kv.z; kt[d + 3][r] = kv.w;
                float4 vv = *(const float4*)&Vb[(size_t)(k0 + r) * DK_ + d];
                *(float4*)&vs[r][d] = vv;
            }
        }
        __syncthreads();

        // ---- scores: s = Q_tile @ K_tile^T ----
        float s[4][4] = {};
        #pragma unroll 8
        for (int d = 0; d < 64; ++d) {
            float4 a  = *(const float4*)&qt[d][tm * 4];
            float4 bk = *(const float4*)&kt[d][tn * 4];
            float av[4] = {a.x, a.y, a.z, a.w};
            float bv[4] = {bk.x, bk.y, bk.z, bk.w};
            #pragma unroll
            for (int i = 0; i < 4; ++i)
                #pragma unroll
                for (int j = 0; j < 4; ++j)
                    s[i][j] = fmaf(av[i], bv[j], s[i][j]);
        }

        // ---- scale + causal mask (exactly like reference) ----
        #pragma unroll
        for (int i = 0; i < 4; ++i)
            #pragma unroll
            for (int j = 0; j < 4; ++j) {
                const int qg = q0 + tm * 4 + i;
                const int kg = k0 + tn * 4 + j;
                const float v = s[i][j] * SCALE_;
                s[i][j] = (kg > qg) ? MASKV_ : v;
            }

        // ---- online softmax, row stats over 16-lane groups ----
        float alpha[4];
        float p[4][4];
        #pragma unroll
        for (int i = 0; i < 4; ++i) {
            float rm = fmaxf(fmaxf(s[i][0], s[i][1]), fmaxf(s[i][2], s[i][3]));
            rm = fmaxf(rm, __shfl_xor(rm, 1, 16));
            rm = fmaxf(rm, __shfl_xor(rm, 2, 16));
            rm = fmaxf(rm, __shfl_xor(rm, 4, 16));
            rm = fmaxf(rm, __shfl_xor(rm, 8, 16));
            const float mnew = fmaxf(mrun[i], rm);
            alpha[i] = expf(mrun[i] - mnew);    // first tile: exp(-inf)=0
            float ls = 0.0f;
            #pragma unroll
            for (int j = 0; j < 4; ++j) {
                p[i][j] = expf(s[i][j] - mnew); // masked: exp(-1e9-m)=0
                ls += p[i][j];
            }
            ls += __shfl_xor(ls, 1, 16);
            ls += __shfl_xor(ls, 2, 16);
            ls += __shfl_xor(ls, 4, 16);
            ls += __shfl_xor(ls, 8, 16);
            lrun[i] = lrun[i] * alpha[i] + ls;
            mrun[i] = mnew;
        }

        // write P transposed: pt[k][m]
        #pragma unroll
        for (int j = 0; j < 4; ++j)
            #pragma unroll
            for (int i = 0; i < 4; ++i)
                pt[tn * 4 + j][tm * 4 + i] = p[i][j];

        // rescale O
        #pragma unroll
        for (int i = 0; i < 4; ++i)
            #pragma unroll
            for (int j = 0; j < 4; ++j)
                o[i][j] *= alpha[i];

        __syncthreads();

        // ---- O += P @ V ----
        #pragma unroll 8
        for (int k = 0; k < 64; ++k) {
            float4 a  = *(const float4*)&pt[k][tm * 4];
            float4 vv = *(const float4*)&vs[k][tn * 4];
            float av[4] = {a.x, a.y, a.z, a.w};
            float bv[4] = {vv.x, vv.y, vv.z, vv.w};
            #pragma unroll
            for (int i = 0; i < 4; ++i)
                #pragma unroll
                for (int j = 0; j < 4; ++j)
                    o[i][j] = fmaf(av[i], bv[j], o[i][j]);
        }
    }

    // ---- epilogue: normalize (matches reference e/(sum+1e-8)), write ctx [B,S,D]
    #pragma unroll
    for (int i = 0; i < 4; ++i) {
        const float inv = 1.0f / (lrun[i] + 1e-8f);
        const int q = q0 + tm * 4 + i;
        float4 r;
        r.x = o[i][0] * inv; r.y = o[i][1] * inv;
        r.z = o[i][2] * inv; r.w = o[i][3] * inv;
        *(float4*)&ctx[(size_t)(b * S_ + q) * D_ + h * DK_ + tn * 4] = r;
    }
}

// ---------------------------------------------------------------------------
extern "C" void kernel_launch(void* const* d_in, const int* in_sizes, int n_in,
                              void* d_out, int out_size, void* d_ws, size_t ws_size,
                              hipStream_t stream)
{
    const float* x  = (const float*)d_in[0];
    const float* Wq = (const float*)d_in[1];
    const float* bq = (const float*)d_in[2];
    const float* Wk = (const float*)d_in[3];
    const float* bk = (const float*)d_in[4];
    const float* Wv = (const float*)d_in[5];
    const float* bv = (const float*)d_in[6];
    const float* Wo = (const float*)d_in[7];
    const float* bo = (const float*)d_in[8];
    // d_in[9] = causal mask; implemented analytically.

    float* out = (float*)d_out;
    float* ws  = (float*)d_ws;

    const size_t PER = (size_t)B_ * H_ * S_ * DK_;  // 4,194,304 floats
    float* Qh  = ws;
    float* Kh  = ws + PER;
    float* Vh  = ws + 2 * PER;
    float* ctx = ws + 3 * PER;

    dim3 blk(256);
    dim3 gproj(D_ / 64, (B_ * S_) / 64);   // (16, 64)
    proj_kernel<<<gproj, blk, 0, stream>>>(x, Wq, bq, Qh, 1);
    proj_kernel<<<gproj, blk, 0, stream>>>(x, Wk, bk, Kh, 1);
    proj_kernel<<<gproj, blk, 0, stream>>>(x, Wv, bv, Vh, 1);

    dim3 gattn(S_ / 64, H_, B_);
    attn_kernel<<<gattn, blk, 0, stream>>>(Qh, Kh, Vh, ctx);

    proj_kernel<<<gproj, blk, 0, stream>>>(ctx, Wo, bo, out, 0);
}

// Round 3
// 434.663 us; speedup vs baseline: 2.5286x; 2.5286x over previous
//
#include <hip/hip_runtime.h>
#include <math.h>

typedef float v4f __attribute__((ext_vector_type(4)));
typedef __bf16 v8y __attribute__((ext_vector_type(8)));
typedef __attribute__((address_space(1))) const void av1_t;
typedef __attribute__((address_space(3))) void av3_t;
typedef unsigned short u16;

#define SCALE_ 0.125f
#define MASKV_ (-1.0e9f)

// truncation split: x ~= bf(hi) + bf(lo), residual ~2^-16 * |x|
__device__ __forceinline__ u16 bfhi(float f) {
  union { float f; unsigned u; } v; v.f = f;
  return (u16)(v.u >> 16);
}
__device__ __forceinline__ float bf2f(u16 h) {
  union { unsigned u; float f; } v; v.u = ((unsigned)h) << 16;
  return v.f;
}
__device__ __forceinline__ v4f mfma16(v8y a, v8y b, v4f c) {
  return __builtin_amdgcn_mfma_f32_16x16x32_bf16(a, b, c, 0, 0, 0);
}
__device__ __forceinline__ void gload16(const void* g, void* l) {
  __builtin_amdgcn_global_load_lds((av1_t*)g, (av3_t*)l, 16, 0, 0);
}

// ---------------------------------------------------------------------------
// split: src [nrow][1024] f32 -> dst [nrow][2048] bf16 = [hi(1024) | lo(1024)]
// ---------------------------------------------------------------------------
__global__ __launch_bounds__(256) void split_kernel(const float* __restrict__ src,
                                                    u16* __restrict__ dst) {
  const int idx = blockIdx.x * 256 + threadIdx.x;
  const int row = idx >> 8, c4 = idx & 255;
  const float4 v = ((const float4*)src)[idx];
  const u16 h0 = bfhi(v.x), h1 = bfhi(v.y), h2 = bfhi(v.z), h3 = bfhi(v.w);
  ushort4 hi, lo;
  hi.x = h0; hi.y = h1; hi.z = h2; hi.w = h3;
  lo.x = bfhi(v.x - bf2f(h0)); lo.y = bfhi(v.y - bf2f(h1));
  lo.z = bfhi(v.z - bf2f(h2)); lo.w = bfhi(v.w - bf2f(h3));
  *(ushort4*)&dst[(size_t)row * 2048 + c4 * 4] = hi;
  *(ushort4*)&dst[(size_t)row * 2048 + 1024 + c4 * 4] = lo;
}

// ---------------------------------------------------------------------------
// GEMM  Y[m][n] = sum_k A[m][k]*B[n][k] + bias, hi/lo split: logical K = 3072
// = sections {A:hi,hi,lo} x {B:hi,lo,hi}. 128x128 tile, BK=64, 4 waves,
// global_load_lds staging, XOR chunk swizzle via pre-swizzled global source.
// mode 0: f32 out [M][1024].  mode 1: QKV split-layout writes.
// ---------------------------------------------------------------------------
__global__ __launch_bounds__(256) void gemm_kernel(
    const u16* __restrict__ A2, const u16* __restrict__ B2,
    const float* __restrict__ bias0, const float* __restrict__ bias1,
    const float* __restrict__ bias2,
    float* __restrict__ outF,
    u16* __restrict__ Q2, u16* __restrict__ K2,
    u16* __restrict__ Vthi, u16* __restrict__ Vtlo,
    int ntiles_n, int mode)
{
  __shared__ __align__(16) u16 sm[16384];  // A tile [0,16384)B, B tile [16384,32768)B
  const int tid = threadIdx.x;
  const int lane = tid & 63;
  const int wid = tid >> 6;
  const int wm = wid >> 1, wn = wid & 1;

  int bid = blockIdx.x;
  const int cpx = gridDim.x >> 3;
  bid = (bid & 7) * cpx + (bid >> 3);      // XCD-bijective (grid % 8 == 0)
  const int mt = bid / ntiles_n, nt = bid % ntiles_n;
  const int m0 = mt * 128, n0 = nt * 128;

  v4f acc[4][4];
  #pragma unroll
  for (int i = 0; i < 4; ++i)
    #pragma unroll
    for (int j = 0; j < 4; ++j) { v4f z = {0.f, 0.f, 0.f, 0.f}; acc[i][j] = z; }

  for (int t = 0; t < 48; ++t) {
    const int aoff = (t < 16 ? t : t - 16) * 64;   // A: hi,hi,lo
    const int boff = (t < 32 ? t : t - 32) * 64;   // B: hi,lo,hi
    __syncthreads();
    #pragma unroll
    for (int p = 0; p < 4; ++p) {
      const int u = p * 256 + tid;          // 16B unit: row = u>>3, phys chunk = u&7
      const int row = u >> 3, cph = u & 7;
      const int clog = cph ^ (row & 7);     // inverse swizzle on global source
      char* lbaseA = (char*)sm + (p * 256 + wid * 64) * 16;
      char* lbaseB = (char*)sm + 16384 + (p * 256 + wid * 64) * 16;
      gload16(&A2[(size_t)(m0 + row) * 2048 + aoff + clog * 8], lbaseA);
      gload16(&B2[(size_t)(n0 + row) * 2048 + boff + clog * 8], lbaseB);
    }
    __syncthreads();
    #pragma unroll
    for (int kc = 0; kc < 2; ++kc) {
      v8y af[4];
      #pragma unroll
      for (int i = 0; i < 4; ++i) {
        const int row = wm * 64 + i * 16 + (lane & 15);
        const int ch = (kc * 4 + (lane >> 4)) ^ (row & 7);
        af[i] = *(const v8y*)((const char*)sm + row * 128 + ch * 16);
      }
      #pragma unroll
      for (int j = 0; j < 4; ++j) {
        const int row = wn * 64 + j * 16 + (lane & 15);
        const int ch = (kc * 4 + (lane >> 4)) ^ (row & 7);
        const v8y bf = *(const v8y*)((const char*)sm + 16384 + row * 128 + ch * 16);
        #pragma unroll
        for (int i = 0; i < 4; ++i)
          acc[i][j] = mfma16(af[i], bf, acc[i][j]);
      }
    }
  }

  // epilogue. D layout: col = lane&15, row = (lane>>4)*4 + r
  #pragma unroll
  for (int i = 0; i < 4; ++i) {
    #pragma unroll
    for (int j = 0; j < 4; ++j) {
      #pragma unroll
      for (int r = 0; r < 4; ++r) {
        const int m = m0 + wm * 64 + i * 16 + (lane >> 4) * 4 + r;
        const int n = n0 + wn * 64 + j * 16 + (lane & 15);
        float y = acc[i][j][r];
        if (mode == 0) {
          outF[(size_t)m * 1024 + n] = y + bias0[n];
        } else {
          const int which = n >> 10;
          const int nn = n & 1023;
          const int hh = nn >> 6, dk = n & 63;
          const int b = m >> 11, s = m & 2047;
          y += (which == 0 ? bias0[nn] : (which == 1 ? bias1[nn] : bias2[nn]));
          const u16 hi = bfhi(y);
          const u16 lo = bfhi(y - bf2f(hi));
          const size_t bh = (size_t)(b * 16 + hh);
          if (which == 2) {         // V stored transposed: [bh][dk][s]
            const size_t a = (bh * 64 + dk) * 2048 + s;
            Vthi[a] = hi; Vtlo[a] = lo;
          } else {                  // Q/K: [bh][s][128] = [hi(64)|lo(64)]
            u16* dst = (which == 0) ? Q2 : K2;
            const size_t a = (bh * 2048 + s) * 128 + dk;
            dst[a] = hi; dst[a + 64] = lo;
          }
        }
      }
    }
  }
}

// ---------------------------------------------------------------------------
// Flash attention, bf16-split MFMA. 256 thr (4 waves), q-tile 64 (16 rows per
// wave), k-tile 64. Causal balance: block does q-tiles (bx, 31-bx) -> 33
// k-tiles each; 512 blocks -> 2 blocks/CU (48KB LDS), 2 waves/SIMD.
// LDS: K[64][128]u16 @0, Vt @16KB, P(4 waves x 16x128) @32KB, XOR-swizzled.
// ---------------------------------------------------------------------------
__global__ __launch_bounds__(256) void attn_kernel(
    const u16* __restrict__ Q2, const u16* __restrict__ K2,
    const u16* __restrict__ Vthi, const u16* __restrict__ Vtlo,
    u16* __restrict__ ctx2)
{
  __shared__ __align__(16) u16 sm[24576];   // 49152 bytes
  const int tid = threadIdx.x, lane = tid & 63, wid = tid >> 6;
  const int h = blockIdx.y, b = blockIdx.z;
  const size_t bh = (size_t)(b * 16 + h);
  const u16* Qb = Q2 + bh * 2048 * 128;
  const u16* Kb = K2 + bh * 2048 * 128;
  const u16* Vhb = Vthi + bh * (size_t)64 * 2048;
  const u16* Vlb = Vtlo + bh * (size_t)64 * 2048;

  #pragma unroll 1
  for (int half = 0; half < 2; ++half) {
    const int qt = (half == 0) ? (int)blockIdx.x : 31 - (int)blockIdx.x;
    const int q0 = qt * 64;

    // hoist Q fragments: phys chunks 0..3 over [hi|lo]
    v8y qf[4];
    #pragma unroll
    for (int pc = 0; pc < 4; ++pc)
      qf[pc] = *(const v8y*)&Qb[(size_t)(q0 + wid * 16 + (lane & 15)) * 128
                                + pc * 32 + (lane >> 4) * 8];

    v4f o[4];
    float mrun[4], lrun[4];
    #pragma unroll
    for (int nb = 0; nb < 4; ++nb) { v4f z = {0.f,0.f,0.f,0.f}; o[nb] = z; }
    #pragma unroll
    for (int r = 0; r < 4; ++r) { mrun[r] = -INFINITY; lrun[r] = 0.f; }

    for (int kb = 0; kb <= qt; ++kb) {
      const int k0 = kb * 64;
      __syncthreads();
      // stage K tile + Vt tile (reg-staged, XOR chunk swizzle)
      #pragma unroll
      for (int p = 0; p < 4; ++p) {
        const int u = p * 256 + tid;        // row = u>>4, logical chunk = u&15
        const int row = u >> 4, c = u & 15;
        const int cph = c ^ (row & 7);
        const uint4 kv = *(const uint4*)&Kb[(size_t)(k0 + row) * 128 + c * 8];
        *(uint4*)((char*)sm + row * 256 + cph * 16) = kv;
        const uint4 vv = (c < 8)
            ? *(const uint4*)&Vhb[(size_t)row * 2048 + k0 + c * 8]
            : *(const uint4*)&Vlb[(size_t)row * 2048 + k0 + (c - 8) * 8];
        *(uint4*)((char*)sm + 16384 + row * 256 + cph * 16) = vv;
      }
      __syncthreads();

      // S = Q K^T : logical kc 0..5, A map {0,1,0,1,2,3}, B map {0,1,2,3,0,1}
      v4f s[4];
      #pragma unroll
      for (int nb = 0; nb < 4; ++nb) { v4f z = {0.f,0.f,0.f,0.f}; s[nb] = z; }
      #pragma unroll
      for (int kc = 0; kc < 6; ++kc) {
        const int ma = (kc < 2) ? kc : kc - 2;
        const int mb = (kc < 4) ? kc : kc - 4;
        #pragma unroll
        for (int nb = 0; nb < 4; ++nb) {
          const int row = nb * 16 + (lane & 15);
          const int ch = (mb * 4 + (lane >> 4)) ^ (row & 7);
          const v8y kf = *(const v8y*)((const char*)sm + row * 256 + ch * 16);
          s[nb] = mfma16(qf[ma], kf, s[nb]);
        }
      }

      // scale + causal mask + online softmax + P hi/lo to LDS
      const bool domask = (kb == qt);
      float alpha[4];
      char* pbase = (char*)sm + 32768 + wid * 4096;
      #pragma unroll
      for (int r = 0; r < 4; ++r) {
        float sv[4];
        #pragma unroll
        for (int nb = 0; nb < 4; ++nb) {
          float v = s[nb][r] * SCALE_;
          if (domask) {
            const int qg = q0 + wid * 16 + (lane >> 4) * 4 + r;
            const int kg = k0 + nb * 16 + (lane & 15);
            if (kg > qg) v = MASKV_;
          }
          sv[nb] = v;
        }
        float rm = fmaxf(fmaxf(sv[0], sv[1]), fmaxf(sv[2], sv[3]));
        rm = fmaxf(rm, __shfl_xor(rm, 1));
        rm = fmaxf(rm, __shfl_xor(rm, 2));
        rm = fmaxf(rm, __shfl_xor(rm, 4));
        rm = fmaxf(rm, __shfl_xor(rm, 8));
        const float mnew = fmaxf(mrun[r], rm);
        const float al = __expf(mrun[r] - mnew);   // first tile: exp(-inf)=0
        const int pr = (lane >> 4) * 4 + r;
        char* prow = pbase + pr * 256;
        float ls = 0.f;
        #pragma unroll
        for (int nb = 0; nb < 4; ++nb) {
          const float pv = __expf(sv[nb] - mnew);  // masked: exp(-1e9-m)=0
          ls += pv;
          const u16 phi = bfhi(pv);
          const u16 plo = bfhi(pv - bf2f(phi));
          const int kp = nb * 16 + (lane & 15);
          *(u16*)(prow + (((kp >> 3)       ^ (pr & 7)) * 16) + (kp & 7) * 2) = phi;
          *(u16*)(prow + (((8 + (kp >> 3)) ^ (pr & 7)) * 16) + (kp & 7) * 2) = plo;
        }
        ls += __shfl_xor(ls, 1);
        ls += __shfl_xor(ls, 2);
        ls += __shfl_xor(ls, 4);
        ls += __shfl_xor(ls, 8);
        lrun[r] = lrun[r] * al + ls;
        mrun[r] = mnew;
        alpha[r] = al;
      }
      #pragma unroll
      for (int nb = 0; nb < 4; ++nb)
        #pragma unroll
        for (int r = 0; r < 4; ++r)
          o[nb][r] *= alpha[r];

      // O += P V   (P is per-wave private; within-wave LDS ordering via lgkmcnt)
      #pragma unroll
      for (int kc = 0; kc < 6; ++kc) {
        const int ma = (kc < 2) ? kc : kc - 2;
        const int mb = (kc < 4) ? kc : kc - 4;
        const int prow_r = lane & 15;
        const int pch = (ma * 4 + (lane >> 4)) ^ (prow_r & 7);
        const v8y pf = *(const v8y*)(pbase + prow_r * 256 + pch * 16);
        #pragma unroll
        for (int nb = 0; nb < 4; ++nb) {
          const int row = nb * 16 + (lane & 15);
          const int ch = (mb * 4 + (lane >> 4)) ^ (row & 7);
          const v8y vf = *(const v8y*)((const char*)sm + 16384 + row * 256 + ch * 16);
          o[nb] = mfma16(pf, vf, o[nb]);
        }
      }
    }

    // epilogue: normalize (matches reference e/(sum+1e-8)), split, write ctx2
    #pragma unroll
    for (int r = 0; r < 4; ++r) {
      const float inv = 1.0f / (lrun[r] + 1e-8f);
      const int q = q0 + wid * 16 + (lane >> 4) * 4 + r;
      const size_t mrow = (size_t)(b * 2048 + q) * 2048;
      #pragma unroll
      for (int nb = 0; nb < 4; ++nb) {
        const float y = o[nb][r] * inv;
        const u16 hi = bfhi(y);
        const u16 lo = bfhi(y - bf2f(hi));
        const int col = h * 64 + nb * 16 + (lane & 15);
        ctx2[mrow + col] = hi;
        ctx2[mrow + 1024 + col] = lo;
      }
    }
  }
}

// ---------------------------------------------------------------------------
// Workspace plan (exactly 67,108,864 B = R0-proven footprint):
//   ws:  Q2(16.8M) K2(16.8M) Vthi(8.4M) Vtlo(8.4M) ctx2(16.8M)
//   W2  aliases ctx2  (dead before attention writes ctx2)
//   Wo2 aliases Q2    (split AFTER attention finishes reading Q2)
//   X2  lives in d_out (dead before final GEMM overwrites d_out)
// ---------------------------------------------------------------------------
extern "C" void kernel_launch(void* const* d_in, const int* in_sizes, int n_in,
                              void* d_out, int out_size, void* d_ws, size_t ws_size,
                              hipStream_t stream)
{
  const float* x  = (const float*)d_in[0];
  const float* Wq = (const float*)d_in[1];
  const float* bq = (const float*)d_in[2];
  const float* Wk = (const float*)d_in[3];
  const float* bk = (const float*)d_in[4];
  const float* Wv = (const float*)d_in[5];
  const float* bv = (const float*)d_in[6];
  const float* Wo = (const float*)d_in[7];
  const float* bo = (const float*)d_in[8];
  // d_in[9] = causal mask; implemented analytically.

  u16* wsp  = (u16*)d_ws;
  u16* Q2   = wsp;                            // [32][2048][128]
  u16* K2   = Q2 + (size_t)32 * 2048 * 128;
  u16* Vthi = K2 + (size_t)32 * 2048 * 128;   // [32][64][2048]
  u16* Vtlo = Vthi + (size_t)32 * 64 * 2048;
  u16* ctx2 = Vtlo + (size_t)32 * 64 * 2048;  // [4096][2048]
  u16* W2   = ctx2;                           // alias
  u16* Wo2  = Q2;                             // alias
  u16* X2   = (u16*)d_out;                    // alias

  split_kernel<<<4096, 256, 0, stream>>>(x, X2);
  split_kernel<<<1024, 256, 0, stream>>>(Wq, W2);
  split_kernel<<<1024, 256, 0, stream>>>(Wk, W2 + (size_t)1024 * 2048);
  split_kernel<<<1024, 256, 0, stream>>>(Wv, W2 + (size_t)2048 * 2048);

  // fused QKV projection: M=4096, N=3072, Klog=3072
  gemm_kernel<<<768, 256, 0, stream>>>(X2, W2, bq, bk, bv,
                                       nullptr, Q2, K2, Vthi, Vtlo, 24, 1);

  attn_kernel<<<dim3(16, 16, 2), 256, 0, stream>>>(Q2, K2, Vthi, Vtlo, ctx2);

  split_kernel<<<1024, 256, 0, stream>>>(Wo, Wo2);

  // output projection: M=4096, N=1024, Klog=3072
  gemm_kernel<<<256, 256, 0, stream>>>(ctx2, Wo2, bo, nullptr, nullptr,
                                       (float*)d_out, nullptr, nullptr, nullptr, nullptr,
                                       8, 0);
}

// Round 4
// 412.419 us; speedup vs baseline: 2.6650x; 1.0539x over previous
//
#include <hip/hip_runtime.h>
#include <math.h>

typedef float v4f __attribute__((ext_vector_type(4)));
typedef __bf16 v8y __attribute__((ext_vector_type(8)));
typedef __attribute__((address_space(1))) const void av1_t;
typedef __attribute__((address_space(3))) void av3_t;
typedef unsigned short u16;

#define SCALE_ 0.125f
#define MASKV_ (-1.0e9f)

// truncation split: x ~= bf(hi) + bf(lo), residual ~2^-16 * |x|
__device__ __forceinline__ u16 bfhi(float f) {
  union { float f; unsigned u; } v; v.f = f;
  return (u16)(v.u >> 16);
}
__device__ __forceinline__ float bf2f(u16 h) {
  union { unsigned u; float f; } v; v.u = ((unsigned)h) << 16;
  return v.f;
}
__device__ __forceinline__ v4f mfma16(v8y a, v8y b, v4f c) {
  return __builtin_amdgcn_mfma_f32_16x16x32_bf16(a, b, c, 0, 0, 0);
}
__device__ __forceinline__ void gload16(const void* g, void* l) {
  __builtin_amdgcn_global_load_lds((av1_t*)g, (av3_t*)l, 16, 0, 0);
}

// ---------------------------------------------------------------------------
// split: src [nrow][1024] f32 -> dst [nrow][2048] bf16 = [hi(1024) | lo(1024)]
// ---------------------------------------------------------------------------
__global__ __launch_bounds__(256) void split_kernel(const float* __restrict__ src,
                                                    u16* __restrict__ dst) {
  const int idx = blockIdx.x * 256 + threadIdx.x;
  const int row = idx >> 8, c4 = idx & 255;
  const float4 v = ((const float4*)src)[idx];
  const u16 h0 = bfhi(v.x), h1 = bfhi(v.y), h2 = bfhi(v.z), h3 = bfhi(v.w);
  ushort4 hi, lo;
  hi.x = h0; hi.y = h1; hi.z = h2; hi.w = h3;
  lo.x = bfhi(v.x - bf2f(h0)); lo.y = bfhi(v.y - bf2f(h1));
  lo.z = bfhi(v.z - bf2f(h2)); lo.w = bfhi(v.w - bf2f(h3));
  *(ushort4*)&dst[(size_t)row * 2048 + c4 * 4] = hi;
  *(ushort4*)&dst[(size_t)row * 2048 + 1024 + c4 * 4] = lo;
}

// ---------------------------------------------------------------------------
// 8-phase 256x256 QKV GEMM (T2+T3+T4+T5). Y = X @ W^T + bias, hi/lo split:
// logical K = 3072 over 48 BK-64 tiles, sections {A:hi,hi,lo}x{B:hi,lo,hi}.
// 512 thr = 8 waves (2M x 4N), per-wave 128x64 out = acc[8][4].
// LDS 128KB: A dbuf 2x(2 kc-halves x 256x32 bf16), B same at +64KB.
// Per tile: 4 phases {ds_read subtile | stage 1 half | barrier | 16 MFMA |
// barrier}; vmcnt(4) only at phases 1,3 (counted, never 0 mid-loop).
// Swizzle: 16B chunk c -> (c + (row>>1)) & 3 (2-way on ds_read = free);
// inverse applied on global source, LDS dest linear (G21).
// ---------------------------------------------------------------------------
__global__ __launch_bounds__(512, 2) void gemm8_kernel(
    const u16* __restrict__ A2, const u16* __restrict__ B2,
    const float* __restrict__ bias0, const float* __restrict__ bias1,
    const float* __restrict__ bias2,
    u16* __restrict__ Q2, u16* __restrict__ K2,
    u16* __restrict__ Vthi, u16* __restrict__ Vtlo)
{
  __shared__ __align__(16) u16 sm[65536];   // 131072 bytes
  char* smc = (char*)sm;
  const int tid = threadIdx.x, lane = tid & 63, wid = tid >> 6;
  const int wm = wid >> 2, wn = wid & 3;
  const int l15 = lane & 15, ck = lane >> 4;

  int bid = blockIdx.x;
  const int cpx = gridDim.x >> 3;            // grid 192 % 8 == 0 -> bijective
  bid = (bid & 7) * cpx + (bid >> 3);
  const int mt = bid / 12, nt = bid % 12;
  const int m0 = mt * 256, n0 = nt * 256;

  // fragment LDS byte offsets (within a (buf,kc) 16KB slab)
  int offA[8], offB[4];
  #pragma unroll
  for (int i = 0; i < 8; ++i) {
    const int row = wm * 128 + i * 16 + l15;
    offA[i] = row * 64 + (((ck + ((row >> 1) & 3)) & 3) * 16);
  }
  #pragma unroll
  for (int j = 0; j < 4; ++j) {
    const int row = wn * 64 + j * 16 + l15;
    offB[j] = row * 64 + (((ck + ((row >> 1) & 3)) & 3) * 16);
  }

  // staging constants: thread covers rows srow and srow+128 of a half-tile
  const int srow = tid >> 2, spc = tid & 3;
  const int sc = (spc - ((srow >> 1) & 3)) & 3;           // inverse swizzle
  const size_t gA0 = (size_t)(m0 + srow) * 2048 + sc * 8;
  const size_t gB0 = (size_t)(n0 + srow) * 2048 + sc * 8;
  const int ldst0 = wid * 64 * 16;                        // + lane*16 implicit

  #define STAGE_(G, gbase, col, lds_off)                                      \
    do {                                                                      \
      gload16(&G[(gbase) + (col)], smc + (lds_off) + ldst0);                  \
      gload16(&G[(gbase) + (col) + 128 * 2048], smc + (lds_off) + ldst0 + 8192); \
    } while (0)

  v4f acc[8][4];
  #pragma unroll
  for (int i = 0; i < 8; ++i)
    #pragma unroll
    for (int j = 0; j < 4; ++j) { v4f z = {0.f, 0.f, 0.f, 0.f}; acc[i][j] = z; }

  // prologue: tile 0 -> buf0 (Akc0, Bkc0, Akc1, Bkc1)
  {
    const int a0 = 0, b0 = 0;                 // tile0: A hi, B hi, ts=0
    STAGE_(A2, gA0, a0, 0);
    STAGE_(B2, gB0, b0, 65536);
    STAGE_(A2, gA0, a0 + 32, 16384);
    STAGE_(B2, gB0, b0 + 32, 65536 + 16384);
  }
  asm volatile("s_waitcnt vmcnt(4)" ::: "memory");
  __builtin_amdgcn_s_barrier();

  #pragma unroll 1
  for (int t = 0; t < 48; ++t) {
    const int buf = t & 1;
    const char* Ac0 = smc + buf * 32768;
    const char* Bc0 = smc + 65536 + buf * 32768;
    const char* Ac1 = Ac0 + 16384;
    const char* Bc1 = Bc0 + 16384;
    const int nbA = (buf ^ 1) * 32768;
    const int nbB = 65536 + (buf ^ 1) * 32768;
    const int t1 = t + 1;
    const bool pf = (t1 < 48);
    const int an = (t1 < 32 ? 0 : 1024) + (t1 & 15) * 64;
    const int bn = ((t1 >= 16 && t1 < 32) ? 1024 : 0) + (t1 & 15) * 64;

    v8y a[4], b[4];
    // ---- phase 0: m0-3 x n0-3 x kc0 ----
    #pragma unroll
    for (int i = 0; i < 4; ++i) a[i] = *(const v8y*)(Ac0 + offA[i]);
    #pragma unroll
    for (int j = 0; j < 4; ++j) b[j] = *(const v8y*)(Bc0 + offB[j]);
    if (pf) STAGE_(A2, gA0, an, nbA);
    __builtin_amdgcn_s_barrier();
    __builtin_amdgcn_s_setprio(1);
    #pragma unroll
    for (int j = 0; j < 4; ++j)
      #pragma unroll
      for (int i = 0; i < 4; ++i)
        acc[i][j] = mfma16(a[i], b[j], acc[i][j]);
    __builtin_amdgcn_s_setprio(0);
    __builtin_amdgcn_s_barrier();

    // ---- phase 1: m4-7 x n0-3 x kc0 ----
    #pragma unroll
    for (int i = 0; i < 4; ++i) a[i] = *(const v8y*)(Ac0 + offA[4 + i]);
    if (pf) {
      STAGE_(B2, gB0, bn, nbB);
      asm volatile("s_waitcnt vmcnt(4)" ::: "memory");   // kc1(t) landed
    } else {
      asm volatile("s_waitcnt vmcnt(0)" ::: "memory");
    }
    __builtin_amdgcn_s_barrier();
    __builtin_amdgcn_s_setprio(1);
    #pragma unroll
    for (int j = 0; j < 4; ++j)
      #pragma unroll
      for (int i = 0; i < 4; ++i)
        acc[4 + i][j] = mfma16(a[i], b[j], acc[4 + i][j]);
    __builtin_amdgcn_s_setprio(0);
    __builtin_amdgcn_s_barrier();

    // ---- phase 2: m0-3 x n0-3 x kc1 ----
    #pragma unroll
    for (int i = 0; i < 4; ++i) a[i] = *(const v8y*)(Ac1 + offA[i]);
    #pragma unroll
    for (int j = 0; j < 4; ++j) b[j] = *(const v8y*)(Bc1 + offB[j]);
    if (pf) STAGE_(A2, gA0, an + 32, nbA + 16384);
    __builtin_amdgcn_s_barrier();
    __builtin_amdgcn_s_setprio(1);
    #pragma unroll
    for (int j = 0; j < 4; ++j)
      #pragma unroll
      for (int i = 0; i < 4; ++i)
        acc[i][j] = mfma16(a[i], b[j], acc[i][j]);
    __builtin_amdgcn_s_setprio(0);
    __builtin_amdgcn_s_barrier();

    // ---- phase 3: m4-7 x n0-3 x kc1 ----
    #pragma unroll
    for (int i = 0; i < 4; ++i) a[i] = *(const v8y*)(Ac1 + offA[4 + i]);
    if (pf) {
      STAGE_(B2, gB0, bn + 32, nbB + 16384);
      asm volatile("s_waitcnt vmcnt(4)" ::: "memory");   // kc0(t+1) landed
    }
    __builtin_amdgcn_s_barrier();
    __builtin_amdgcn_s_setprio(1);
    #pragma unroll
    for (int j = 0; j < 4; ++j)
      #pragma unroll
      for (int i = 0; i < 4; ++i)
        acc[4 + i][j] = mfma16(a[i], b[j], acc[4 + i][j]);
    __builtin_amdgcn_s_setprio(0);
    __builtin_amdgcn_s_barrier();
  }
  #undef STAGE_

  // epilogue: QKV split-layout scatter. D: col = lane&15, row = (lane>>4)*4+r
  #pragma unroll
  for (int i = 0; i < 8; ++i) {
    #pragma unroll
    for (int j = 0; j < 4; ++j) {
      #pragma unroll
      for (int r = 0; r < 4; ++r) {
        const int m = m0 + wm * 128 + i * 16 + (lane >> 4) * 4 + r;
        const int n = n0 + wn * 64 + j * 16 + l15;
        float y = acc[i][j][r];
        const int which = n >> 10, nn = n & 1023;
        const int hh = nn >> 6, dk = n & 63;
        const int b_ = m >> 11, s = m & 2047;
        y += (which == 0 ? bias0[nn] : (which == 1 ? bias1[nn] : bias2[nn]));
        const u16 hi = bfhi(y);
        const u16 lo = bfhi(y - bf2f(hi));
        const size_t bh = (size_t)(b_ * 16 + hh);
        if (which == 2) {           // V transposed: [bh][dk][s]
          const size_t a_ = (bh * 64 + dk) * 2048 + s;
          Vthi[a_] = hi; Vtlo[a_] = lo;
        } else {                    // Q/K: [bh][s][128] = [hi(64)|lo(64)]
          u16* dst = (which == 0) ? Q2 : K2;
          const size_t a_ = (bh * 2048 + s) * 128 + dk;
          dst[a_] = hi; dst[a_ + 64] = lo;
        }
      }
    }
  }
}

// ---------------------------------------------------------------------------
// 2-phase 128x128 GEMM (out-projection only). Y = X @ W^T + bias, f32 out.
// ---------------------------------------------------------------------------
__global__ __launch_bounds__(256) void gemm_kernel(
    const u16* __restrict__ A2, const u16* __restrict__ B2,
    const float* __restrict__ bias0,
    float* __restrict__ outF, int ntiles_n)
{
  __shared__ __align__(16) u16 sm[16384];
  const int tid = threadIdx.x;
  const int lane = tid & 63;
  const int wid = tid >> 6;
  const int wm = wid >> 1, wn = wid & 1;

  int bid = blockIdx.x;
  const int cpx = gridDim.x >> 3;
  bid = (bid & 7) * cpx + (bid >> 3);
  const int mt = bid / ntiles_n, nt = bid % ntiles_n;
  const int m0 = mt * 128, n0 = nt * 128;

  v4f acc[4][4];
  #pragma unroll
  for (int i = 0; i < 4; ++i)
    #pragma unroll
    for (int j = 0; j < 4; ++j) { v4f z = {0.f, 0.f, 0.f, 0.f}; acc[i][j] = z; }

  for (int t = 0; t < 48; ++t) {
    const int aoff = (t < 16 ? t : t - 16) * 64;   // A: hi,hi,lo
    const int boff = (t < 32 ? t : t - 32) * 64;   // B: hi,lo,hi
    __syncthreads();
    #pragma unroll
    for (int p = 0; p < 4; ++p) {
      const int u = p * 256 + tid;
      const int row = u >> 3, cph = u & 7;
      const int clog = cph ^ (row & 7);
      char* lbaseA = (char*)sm + (p * 256 + wid * 64) * 16;
      char* lbaseB = (char*)sm + 16384 + (p * 256 + wid * 64) * 16;
      gload16(&A2[(size_t)(m0 + row) * 2048 + aoff + clog * 8], lbaseA);
      gload16(&B2[(size_t)(n0 + row) * 2048 + boff + clog * 8], lbaseB);
    }
    __syncthreads();
    #pragma unroll
    for (int kc = 0; kc < 2; ++kc) {
      v8y af[4];
      #pragma unroll
      for (int i = 0; i < 4; ++i) {
        const int row = wm * 64 + i * 16 + (lane & 15);
        const int ch = (kc * 4 + (lane >> 4)) ^ (row & 7);
        af[i] = *(const v8y*)((const char*)sm + row * 128 + ch * 16);
      }
      #pragma unroll
      for (int j = 0; j < 4; ++j) {
        const int row = wn * 64 + j * 16 + (lane & 15);
        const int ch = (kc * 4 + (lane >> 4)) ^ (row & 7);
        const v8y bf = *(const v8y*)((const char*)sm + 16384 + row * 128 + ch * 16);
        #pragma unroll
        for (int i = 0; i < 4; ++i)
          acc[i][j] = mfma16(af[i], bf, acc[i][j]);
      }
    }
  }

  #pragma unroll
  for (int i = 0; i < 4; ++i) {
    #pragma unroll
    for (int j = 0; j < 4; ++j) {
      #pragma unroll
      for (int r = 0; r < 4; ++r) {
        const int m = m0 + wm * 64 + i * 16 + (lane >> 4) * 4 + r;
        const int n = n0 + wn * 64 + j * 16 + (lane & 15);
        outF[(size_t)m * 1024 + n] = acc[i][j][r] + bias0[n];
      }
    }
  }
}

// ---------------------------------------------------------------------------
// Flash attention, bf16-split MFMA (unchanged from passing R3).
// ---------------------------------------------------------------------------
__global__ __launch_bounds__(256) void attn_kernel(
    const u16* __restrict__ Q2, const u16* __restrict__ K2,
    const u16* __restrict__ Vthi, const u16* __restrict__ Vtlo,
    u16* __restrict__ ctx2)
{
  __shared__ __align__(16) u16 sm[24576];   // 49152 bytes
  const int tid = threadIdx.x, lane = tid & 63, wid = tid >> 6;
  const int h = blockIdx.y, b = blockIdx.z;
  const size_t bh = (size_t)(b * 16 + h);
  const u16* Qb = Q2 + bh * 2048 * 128;
  const u16* Kb = K2 + bh * 2048 * 128;
  const u16* Vhb = Vthi + bh * (size_t)64 * 2048;
  const u16* Vlb = Vtlo + bh * (size_t)64 * 2048;

  #pragma unroll 1
  for (int half = 0; half < 2; ++half) {
    const int qt = (half == 0) ? (int)blockIdx.x : 31 - (int)blockIdx.x;
    const int q0 = qt * 64;

    v8y qf[4];
    #pragma unroll
    for (int pc = 0; pc < 4; ++pc)
      qf[pc] = *(const v8y*)&Qb[(size_t)(q0 + wid * 16 + (lane & 15)) * 128
                                + pc * 32 + (lane >> 4) * 8];

    v4f o[4];
    float mrun[4], lrun[4];
    #pragma unroll
    for (int nb = 0; nb < 4; ++nb) { v4f z = {0.f,0.f,0.f,0.f}; o[nb] = z; }
    #pragma unroll
    for (int r = 0; r < 4; ++r) { mrun[r] = -INFINITY; lrun[r] = 0.f; }

    for (int kb = 0; kb <= qt; ++kb) {
      const int k0 = kb * 64;
      __syncthreads();
      #pragma unroll
      for (int p = 0; p < 4; ++p) {
        const int u = p * 256 + tid;
        const int row = u >> 4, c = u & 15;
        const int cph = c ^ (row & 7);
        const uint4 kv = *(const uint4*)&Kb[(size_t)(k0 + row) * 128 + c * 8];
        *(uint4*)((char*)sm + row * 256 + cph * 16) = kv;
        const uint4 vv = (c < 8)
            ? *(const uint4*)&Vhb[(size_t)row * 2048 + k0 + c * 8]
            : *(const uint4*)&Vlb[(size_t)row * 2048 + k0 + (c - 8) * 8];
        *(uint4*)((char*)sm + 16384 + row * 256 + cph * 16) = vv;
      }
      __syncthreads();

      v4f s[4];
      #pragma unroll
      for (int nb = 0; nb < 4; ++nb) { v4f z = {0.f,0.f,0.f,0.f}; s[nb] = z; }
      #pragma unroll
      for (int kc = 0; kc < 6; ++kc) {
        const int ma = (kc < 2) ? kc : kc - 2;
        const int mb = (kc < 4) ? kc : kc - 4;
        #pragma unroll
        for (int nb = 0; nb < 4; ++nb) {
          const int row = nb * 16 + (lane & 15);
          const int ch = (mb * 4 + (lane >> 4)) ^ (row & 7);
          const v8y kf = *(const v8y*)((const char*)sm + row * 256 + ch * 16);
          s[nb] = mfma16(qf[ma], kf, s[nb]);
        }
      }

      const bool domask = (kb == qt);
      float alpha[4];
      char* pbase = (char*)sm + 32768 + wid * 4096;
      #pragma unroll
      for (int r = 0; r < 4; ++r) {
        float sv[4];
        #pragma unroll
        for (int nb = 0; nb < 4; ++nb) {
          float v = s[nb][r] * SCALE_;
          if (domask) {
            const int qg = q0 + wid * 16 + (lane >> 4) * 4 + r;
            const int kg = k0 + nb * 16 + (lane & 15);
            if (kg > qg) v = MASKV_;
          }
          sv[nb] = v;
        }
        float rm = fmaxf(fmaxf(sv[0], sv[1]), fmaxf(sv[2], sv[3]));
        rm = fmaxf(rm, __shfl_xor(rm, 1));
        rm = fmaxf(rm, __shfl_xor(rm, 2));
        rm = fmaxf(rm, __shfl_xor(rm, 4));
        rm = fmaxf(rm, __shfl_xor(rm, 8));
        const float mnew = fmaxf(mrun[r], rm);
        const float al = __expf(mrun[r] - mnew);
        const int pr = (lane >> 4) * 4 + r;
        char* prow = pbase + pr * 256;
        float ls = 0.f;
        #pragma unroll
        for (int nb = 0; nb < 4; ++nb) {
          const float pv = __expf(sv[nb] - mnew);
          ls += pv;
          const u16 phi = bfhi(pv);
          const u16 plo = bfhi(pv - bf2f(phi));
          const int kp = nb * 16 + (lane & 15);
          *(u16*)(prow + (((kp >> 3)       ^ (pr & 7)) * 16) + (kp & 7) * 2) = phi;
          *(u16*)(prow + (((8 + (kp >> 3)) ^ (pr & 7)) * 16) + (kp & 7) * 2) = plo;
        }
        ls += __shfl_xor(ls, 1);
        ls += __shfl_xor(ls, 2);
        ls += __shfl_xor(ls, 4);
        ls += __shfl_xor(ls, 8);
        lrun[r] = lrun[r] * al + ls;
        mrun[r] = mnew;
        alpha[r] = al;
      }
      #pragma unroll
      for (int nb = 0; nb < 4; ++nb)
        #pragma unroll
        for (int r = 0; r < 4; ++r)
          o[nb][r] *= alpha[r];

      #pragma unroll
      for (int kc = 0; kc < 6; ++kc) {
        const int ma = (kc < 2) ? kc : kc - 2;
        const int mb = (kc < 4) ? kc : kc - 4;
        const int prow_r = lane & 15;
        const int pch = (ma * 4 + (lane >> 4)) ^ (prow_r & 7);
        const v8y pf = *(const v8y*)(pbase + prow_r * 256 + pch * 16);
        #pragma unroll
        for (int nb = 0; nb < 4; ++nb) {
          const int row = nb * 16 + (lane & 15);
          const int ch = (mb * 4 + (lane >> 4)) ^ (row & 7);
          const v8y vf = *(const v8y*)((const char*)sm + 16384 + row * 256 + ch * 16);
          o[nb] = mfma16(pf, vf, o[nb]);
        }
      }
    }

    #pragma unroll
    for (int r = 0; r < 4; ++r) {
      const float inv = 1.0f / (lrun[r] + 1e-8f);
      const int q = q0 + wid * 16 + (lane >> 4) * 4 + r;
      const size_t mrow = (size_t)(b * 2048 + q) * 2048;
      #pragma unroll
      for (int nb = 0; nb < 4; ++nb) {
        const float y = o[nb][r] * inv;
        const u16 hi = bfhi(y);
        const u16 lo = bfhi(y - bf2f(hi));
        const int col = h * 64 + nb * 16 + (lane & 15);
        ctx2[mrow + col] = hi;
        ctx2[mrow + 1024 + col] = lo;
      }
    }
  }
}

// ---------------------------------------------------------------------------
// Workspace plan (exactly 67,108,864 B):
//   ws: Q2(16.8M) K2(16.8M) Vthi(8.4M) Vtlo(8.4M) ctx2(16.8M)
//   W2 aliases ctx2; Wo2 aliases Q2 (split after attn); X2 lives in d_out.
// ---------------------------------------------------------------------------
extern "C" void kernel_launch(void* const* d_in, const int* in_sizes, int n_in,
                              void* d_out, int out_size, void* d_ws, size_t ws_size,
                              hipStream_t stream)
{
  const float* x  = (const float*)d_in[0];
  const float* Wq = (const float*)d_in[1];
  const float* bq = (const float*)d_in[2];
  const float* Wk = (const float*)d_in[3];
  const float* bk = (const float*)d_in[4];
  const float* Wv = (const float*)d_in[5];
  const float* bv = (const float*)d_in[6];
  const float* Wo = (const float*)d_in[7];
  const float* bo = (const float*)d_in[8];
  // d_in[9] = causal mask; implemented analytically.

  u16* wsp  = (u16*)d_ws;
  u16* Q2   = wsp;                            // [32][2048][128]
  u16* K2   = Q2 + (size_t)32 * 2048 * 128;
  u16* Vthi = K2 + (size_t)32 * 2048 * 128;   // [32][64][2048]
  u16* Vtlo = Vthi + (size_t)32 * 64 * 2048;
  u16* ctx2 = Vtlo + (size_t)32 * 64 * 2048;  // [4096][2048]
  u16* W2   = ctx2;                           // alias
  u16* Wo2  = Q2;                             // alias
  u16* X2   = (u16*)d_out;                    // alias

  split_kernel<<<4096, 256, 0, stream>>>(x, X2);
  split_kernel<<<1024, 256, 0, stream>>>(Wq, W2);
  split_kernel<<<1024, 256, 0, stream>>>(Wk, W2 + (size_t)1024 * 2048);
  split_kernel<<<1024, 256, 0, stream>>>(Wv, W2 + (size_t)2048 * 2048);

  // fused QKV projection: M=4096, N=3072, Klog=3072 -> 16x12 = 192 blocks
  gemm8_kernel<<<192, 512, 0, stream>>>(X2, W2, bq, bk, bv,
                                        Q2, K2, Vthi, Vtlo);

  attn_kernel<<<dim3(16, 16, 2), 256, 0, stream>>>(Q2, K2, Vthi, Vtlo, ctx2);

  split_kernel<<<1024, 256, 0, stream>>>(Wo, Wo2);

  // output projection: M=4096, N=1024, Klog=3072
  gemm_kernel<<<256, 256, 0, stream>>>(ctx2, Wo2, bo, (float*)d_out, 8);
}

// Round 5
// 391.873 us; speedup vs baseline: 2.8047x; 1.0524x over previous
//
#include <hip/hip_runtime.h>
#include <math.h>

typedef float v4f __attribute__((ext_vector_type(4)));
typedef __bf16 v8y __attribute__((ext_vector_type(8)));
typedef __attribute__((address_space(1))) const void av1_t;
typedef __attribute__((address_space(3))) void av3_t;
typedef unsigned short u16;

#define SCALE_ 0.125f
#define MASKV_ (-1.0e9f)

// truncation split: x ~= bf(hi) + bf(lo), residual ~2^-16 * |x|
__device__ __forceinline__ u16 bfhi(float f) {
  union { float f; unsigned u; } v; v.f = f;
  return (u16)(v.u >> 16);
}
__device__ __forceinline__ float bf2f(u16 h) {
  union { unsigned u; float f; } v; v.u = ((unsigned)h) << 16;
  return v.f;
}
__device__ __forceinline__ v4f mfma16(v8y a, v8y b, v4f c) {
  return __builtin_amdgcn_mfma_f32_16x16x32_bf16(a, b, c, 0, 0, 0);
}
__device__ __forceinline__ void gload16(const void* g, void* l) {
  __builtin_amdgcn_global_load_lds((av1_t*)g, (av3_t*)l, 16, 0, 0);
}

// ---------------------------------------------------------------------------
// split: src [nrow][1024] f32 -> dst [nrow][2048] bf16 = [hi(1024) | lo(1024)]
// ---------------------------------------------------------------------------
__global__ __launch_bounds__(256) void split_kernel(const float* __restrict__ src,
                                                    u16* __restrict__ dst) {
  const int idx = blockIdx.x * 256 + threadIdx.x;
  const int row = idx >> 8, c4 = idx & 255;
  const float4 v = ((const float4*)src)[idx];
  const u16 h0 = bfhi(v.x), h1 = bfhi(v.y), h2 = bfhi(v.z), h3 = bfhi(v.w);
  ushort4 hi, lo;
  hi.x = h0; hi.y = h1; hi.z = h2; hi.w = h3;
  lo.x = bfhi(v.x - bf2f(h0)); lo.y = bfhi(v.y - bf2f(h1));
  lo.z = bfhi(v.z - bf2f(h2)); lo.w = bfhi(v.w - bf2f(h3));
  *(ushort4*)&dst[(size_t)row * 2048 + c4 * 4] = hi;
  *(ushort4*)&dst[(size_t)row * 2048 + 1024 + c4 * 4] = lo;
}

// fused QKV-weight split: 3072 blocks, one row each
__global__ __launch_bounds__(256) void splitw_kernel(
    const float* __restrict__ Wq, const float* __restrict__ Wk,
    const float* __restrict__ Wv, u16* __restrict__ dst) {
  const int r = blockIdx.x;            // 0..3071
  const int c4 = threadIdx.x;          // 0..255 (float4 chunk)
  const float* src = (r < 1024) ? Wq + (size_t)r * 1024
                   : (r < 2048) ? Wk + (size_t)(r - 1024) * 1024
                                : Wv + (size_t)(r - 2048) * 1024;
  const float4 v = ((const float4*)src)[c4];
  const u16 h0 = bfhi(v.x), h1 = bfhi(v.y), h2 = bfhi(v.z), h3 = bfhi(v.w);
  ushort4 hi, lo;
  hi.x = h0; hi.y = h1; hi.z = h2; hi.w = h3;
  lo.x = bfhi(v.x - bf2f(h0)); lo.y = bfhi(v.y - bf2f(h1));
  lo.z = bfhi(v.z - bf2f(h2)); lo.w = bfhi(v.w - bf2f(h3));
  *(ushort4*)&dst[(size_t)r * 2048 + c4 * 4] = hi;
  *(ushort4*)&dst[(size_t)r * 2048 + 1024 + c4 * 4] = lo;
}

// ---------------------------------------------------------------------------
// 3-pass-per-subtile GEMM. Y[m][n] = sum_k A[m][k]*B[n][k] + bias, hi/lo
// split. 32 subtiles of K-phys 32; per subtile stage quarters
// [Ahi|Alo|Bhi|Blo] (32KB) ONCE, then 3 passes (Ahi*Bhi, Alo*Bhi, Ahi*Blo)
// = 48 MFMA/wave per drain (vs 32 staged-thrice in R3). 128x128 tile,
// 4 waves, global_load_lds, +rotate chunk swizzle (2-way max = free).
// mode 0: f32 out [M][1024].  mode 1: QKV split-layout writes.
// ---------------------------------------------------------------------------
__global__ __launch_bounds__(256) void gemm3_kernel(
    const u16* __restrict__ A2, const u16* __restrict__ B2,
    const float* __restrict__ bias0, const float* __restrict__ bias1,
    const float* __restrict__ bias2,
    float* __restrict__ outF,
    u16* __restrict__ Q2, u16* __restrict__ K2,
    u16* __restrict__ Vthi, u16* __restrict__ Vtlo,
    int ntiles_n, int mode)
{
  __shared__ __align__(16) u16 sm[16384];  // 32KB: Ahi@0 Alo@8K Bhi@16K Blo@24K (bytes)
  char* smc = (char*)sm;
  const int tid = threadIdx.x;
  const int lane = tid & 63;
  const int wid = tid >> 6;
  const int wm = wid >> 1, wn = wid & 1;
  const int l15 = lane & 15, ck = lane >> 4;

  int bid = blockIdx.x;
  const int cpx = gridDim.x >> 3;          // grid % 8 == 0 -> bijective
  bid = (bid & 7) * cpx + (bid >> 3);
  const int mt = bid / ntiles_n, nt = bid % ntiles_n;
  const int m0 = mt * 128, n0 = nt * 128;

  // fragment LDS byte offsets within a quarter (row=64B, +rotate swizzle)
  int offA[4], offB[4];
  #pragma unroll
  for (int i = 0; i < 4; ++i) {
    const int row = wm * 64 + i * 16 + l15;
    offA[i] = row * 64 + (((ck + ((row >> 1) & 3)) & 3) * 16);
  }
  #pragma unroll
  for (int j = 0; j < 4; ++j) {
    const int row = wn * 64 + j * 16 + l15;
    offB[j] = row * 64 + (((ck + ((row >> 1) & 3)) & 3) * 16);
  }

  v4f acc[4][4];
  #pragma unroll
  for (int i = 0; i < 4; ++i)
    #pragma unroll
    for (int j = 0; j < 4; ++j) { v4f z = {0.f, 0.f, 0.f, 0.f}; acc[i][j] = z; }

  #pragma unroll 1
  for (int s = 0; s < 32; ++s) {
    __syncthreads();   // previous subtile's readers done
    // stage quarters: unit u = p*256+tid; qi=p>>1 (0 Ahi,1 Alo,2 Bhi,3 Blo)
    #pragma unroll
    for (int p = 0; p < 8; ++p) {
      const int w = (p & 1) * 256 + tid;
      const int row = w >> 2, cph = w & 3;
      const int clog = (cph - ((row >> 1) & 3)) & 3;   // inverse swizzle on src
      const int qi = p >> 1;
      const u16* src = (qi < 2) ? A2 : B2;
      const int r0 = (qi < 2) ? m0 : n0;
      const int qoff = (qi & 1) * 1024;
      gload16(&src[(size_t)(r0 + row) * 2048 + qoff + s * 32 + clog * 8],
              smc + p * 4096 + wid * 1024);
    }
    __syncthreads();   // compiler drains vmcnt(0) before barrier

    v8y bhi[4], af[4];
    #pragma unroll
    for (int j = 0; j < 4; ++j) bhi[j] = *(const v8y*)(smc + 16384 + offB[j]);

    // pass 0: Ahi x Bhi
    #pragma unroll
    for (int i = 0; i < 4; ++i) af[i] = *(const v8y*)(smc + offA[i]);
    #pragma unroll
    for (int j = 0; j < 4; ++j)
      #pragma unroll
      for (int i = 0; i < 4; ++i)
        acc[i][j] = mfma16(af[i], bhi[j], acc[i][j]);

    // pass 1: Alo x Bhi  (B frags reused in registers)
    #pragma unroll
    for (int i = 0; i < 4; ++i) af[i] = *(const v8y*)(smc + 8192 + offA[i]);
    #pragma unroll
    for (int j = 0; j < 4; ++j)
      #pragma unroll
      for (int i = 0; i < 4; ++i)
        acc[i][j] = mfma16(af[i], bhi[j], acc[i][j]);

    // pass 2: Ahi x Blo
    v8y blo[4];
    #pragma unroll
    for (int j = 0; j < 4; ++j) blo[j] = *(const v8y*)(smc + 24576 + offB[j]);
    #pragma unroll
    for (int i = 0; i < 4; ++i) af[i] = *(const v8y*)(smc + offA[i]);
    #pragma unroll
    for (int j = 0; j < 4; ++j)
      #pragma unroll
      for (int i = 0; i < 4; ++i)
        acc[i][j] = mfma16(af[i], blo[j], acc[i][j]);
  }

  // epilogue. D layout: col = lane&15, row = (lane>>4)*4 + r
  #pragma unroll
  for (int i = 0; i < 4; ++i) {
    #pragma unroll
    for (int j = 0; j < 4; ++j) {
      #pragma unroll
      for (int r = 0; r < 4; ++r) {
        const int m = m0 + wm * 64 + i * 16 + (lane >> 4) * 4 + r;
        const int n = n0 + wn * 64 + j * 16 + (lane & 15);
        float y = acc[i][j][r];
        if (mode == 0) {
          outF[(size_t)m * 1024 + n] = y + bias0[n];
        } else {
          const int which = n >> 10;
          const int nn = n & 1023;
          const int hh = nn >> 6, dk = n & 63;
          const int b = m >> 11, sr = m & 2047;
          y += (which == 0 ? bias0[nn] : (which == 1 ? bias1[nn] : bias2[nn]));
          const u16 hi = bfhi(y);
          const u16 lo = bfhi(y - bf2f(hi));
          const size_t bh = (size_t)(b * 16 + hh);
          if (which == 2) {         // V stored transposed: [bh][dk][s]
            const size_t a = (bh * 64 + dk) * 2048 + sr;
            Vthi[a] = hi; Vtlo[a] = lo;
          } else {                  // Q/K: [bh][s][128] = [hi(64)|lo(64)]
            u16* dst = (which == 0) ? Q2 : K2;
            const size_t a = (bh * 2048 + sr) * 128 + dk;
            dst[a] = hi; dst[a + 64] = lo;
          }
        }
      }
    }
  }
}

// ---------------------------------------------------------------------------
// Flash attention, bf16-split MFMA (unchanged from passing R3/R4).
// ---------------------------------------------------------------------------
__global__ __launch_bounds__(256) void attn_kernel(
    const u16* __restrict__ Q2, const u16* __restrict__ K2,
    const u16* __restrict__ Vthi, const u16* __restrict__ Vtlo,
    u16* __restrict__ ctx2)
{
  __shared__ __align__(16) u16 sm[24576];   // 49152 bytes
  const int tid = threadIdx.x, lane = tid & 63, wid = tid >> 6;
  const int h = blockIdx.y, b = blockIdx.z;
  const size_t bh = (size_t)(b * 16 + h);
  const u16* Qb = Q2 + bh * 2048 * 128;
  const u16* Kb = K2 + bh * 2048 * 128;
  const u16* Vhb = Vthi + bh * (size_t)64 * 2048;
  const u16* Vlb = Vtlo + bh * (size_t)64 * 2048;

  #pragma unroll 1
  for (int half = 0; half < 2; ++half) {
    const int qt = (half == 0) ? (int)blockIdx.x : 31 - (int)blockIdx.x;
    const int q0 = qt * 64;

    v8y qf[4];
    #pragma unroll
    for (int pc = 0; pc < 4; ++pc)
      qf[pc] = *(const v8y*)&Qb[(size_t)(q0 + wid * 16 + (lane & 15)) * 128
                                + pc * 32 + (lane >> 4) * 8];

    v4f o[4];
    float mrun[4], lrun[4];
    #pragma unroll
    for (int nb = 0; nb < 4; ++nb) { v4f z = {0.f,0.f,0.f,0.f}; o[nb] = z; }
    #pragma unroll
    for (int r = 0; r < 4; ++r) { mrun[r] = -INFINITY; lrun[r] = 0.f; }

    for (int kb = 0; kb <= qt; ++kb) {
      const int k0 = kb * 64;
      __syncthreads();
      #pragma unroll
      for (int p = 0; p < 4; ++p) {
        const int u = p * 256 + tid;
        const int row = u >> 4, c = u & 15;
        const int cph = c ^ (row & 7);
        const uint4 kv = *(const uint4*)&Kb[(size_t)(k0 + row) * 128 + c * 8];
        *(uint4*)((char*)sm + row * 256 + cph * 16) = kv;
        const uint4 vv = (c < 8)
            ? *(const uint4*)&Vhb[(size_t)row * 2048 + k0 + c * 8]
            : *(const uint4*)&Vlb[(size_t)row * 2048 + k0 + (c - 8) * 8];
        *(uint4*)((char*)sm + 16384 + row * 256 + cph * 16) = vv;
      }
      __syncthreads();

      v4f s[4];
      #pragma unroll
      for (int nb = 0; nb < 4; ++nb) { v4f z = {0.f,0.f,0.f,0.f}; s[nb] = z; }
      #pragma unroll
      for (int kc = 0; kc < 6; ++kc) {
        const int ma = (kc < 2) ? kc : kc - 2;
        const int mb = (kc < 4) ? kc : kc - 4;
        #pragma unroll
        for (int nb = 0; nb < 4; ++nb) {
          const int row = nb * 16 + (lane & 15);
          const int ch = (mb * 4 + (lane >> 4)) ^ (row & 7);
          const v8y kf = *(const v8y*)((const char*)sm + row * 256 + ch * 16);
          s[nb] = mfma16(qf[ma], kf, s[nb]);
        }
      }

      const bool domask = (kb == qt);
      float alpha[4];
      char* pbase = (char*)sm + 32768 + wid * 4096;
      #pragma unroll
      for (int r = 0; r < 4; ++r) {
        float sv[4];
        #pragma unroll
        for (int nb = 0; nb < 4; ++nb) {
          float v = s[nb][r] * SCALE_;
          if (domask) {
            const int qg = q0 + wid * 16 + (lane >> 4) * 4 + r;
            const int kg = k0 + nb * 16 + (lane & 15);
            if (kg > qg) v = MASKV_;
          }
          sv[nb] = v;
        }
        float rm = fmaxf(fmaxf(sv[0], sv[1]), fmaxf(sv[2], sv[3]));
        rm = fmaxf(rm, __shfl_xor(rm, 1));
        rm = fmaxf(rm, __shfl_xor(rm, 2));
        rm = fmaxf(rm, __shfl_xor(rm, 4));
        rm = fmaxf(rm, __shfl_xor(rm, 8));
        const float mnew = fmaxf(mrun[r], rm);
        const float al = __expf(mrun[r] - mnew);
        const int pr = (lane >> 4) * 4 + r;
        char* prow = pbase + pr * 256;
        float ls = 0.f;
        #pragma unroll
        for (int nb = 0; nb < 4; ++nb) {
          const float pv = __expf(sv[nb] - mnew);
          ls += pv;
          const u16 phi = bfhi(pv);
          const u16 plo = bfhi(pv - bf2f(phi));
          const int kp = nb * 16 + (lane & 15);
          *(u16*)(prow + (((kp >> 3)       ^ (pr & 7)) * 16) + (kp & 7) * 2) = phi;
          *(u16*)(prow + (((8 + (kp >> 3)) ^ (pr & 7)) * 16) + (kp & 7) * 2) = plo;
        }
        ls += __shfl_xor(ls, 1);
        ls += __shfl_xor(ls, 2);
        ls += __shfl_xor(ls, 4);
        ls += __shfl_xor(ls, 8);
        lrun[r] = lrun[r] * al + ls;
        mrun[r] = mnew;
        alpha[r] = al;
      }
      #pragma unroll
      for (int nb = 0; nb < 4; ++nb)
        #pragma unroll
        for (int r = 0; r < 4; ++r)
          o[nb][r] *= alpha[r];

      #pragma unroll
      for (int kc = 0; kc < 6; ++kc) {
        const int ma = (kc < 2) ? kc : kc - 2;
        const int mb = (kc < 4) ? kc : kc - 4;
        const int prow_r = lane & 15;
        const int pch = (ma * 4 + (lane >> 4)) ^ (prow_r & 7);
        const v8y pf = *(const v8y*)(pbase + prow_r * 256 + pch * 16);
        #pragma unroll
        for (int nb = 0; nb < 4; ++nb) {
          const int row = nb * 16 + (lane & 15);
          const int ch = (mb * 4 + (lane >> 4)) ^ (row & 7);
          const v8y vf = *(const v8y*)((const char*)sm + 16384 + row * 256 + ch * 16);
          o[nb] = mfma16(pf, vf, o[nb]);
        }
      }
    }

    #pragma unroll
    for (int r = 0; r < 4; ++r) {
      const float inv = 1.0f / (lrun[r] + 1e-8f);
      const int q = q0 + wid * 16 + (lane >> 4) * 4 + r;
      const size_t mrow = (size_t)(b * 2048 + q) * 2048;
      #pragma unroll
      for (int nb = 0; nb < 4; ++nb) {
        const float y = o[nb][r] * inv;
        const u16 hi = bfhi(y);
        const u16 lo = bfhi(y - bf2f(hi));
        const int col = h * 64 + nb * 16 + (lane & 15);
        ctx2[mrow + col] = hi;
        ctx2[mrow + 1024 + col] = lo;
      }
    }
  }
}

// ---------------------------------------------------------------------------
// Workspace plan (exactly 67,108,864 B):
//   ws: Q2(16.8M) K2(16.8M) Vthi(8.4M) Vtlo(8.4M) ctx2(16.8M)
//   W2 aliases ctx2; Wo2 aliases Q2 (split after attn); X2 lives in d_out.
// ---------------------------------------------------------------------------
extern "C" void kernel_launch(void* const* d_in, const int* in_sizes, int n_in,
                              void* d_out, int out_size, void* d_ws, size_t ws_size,
                              hipStream_t stream)
{
  const float* x  = (const float*)d_in[0];
  const float* Wq = (const float*)d_in[1];
  const float* bq = (const float*)d_in[2];
  const float* Wk = (const float*)d_in[3];
  const float* bk = (const float*)d_in[4];
  const float* Wv = (const float*)d_in[5];
  const float* bv = (const float*)d_in[6];
  const float* Wo = (const float*)d_in[7];
  const float* bo = (const float*)d_in[8];
  // d_in[9] = causal mask; implemented analytically.

  u16* wsp  = (u16*)d_ws;
  u16* Q2   = wsp;                            // [32][2048][128]
  u16* K2   = Q2 + (size_t)32 * 2048 * 128;
  u16* Vthi = K2 + (size_t)32 * 2048 * 128;   // [32][64][2048]
  u16* Vtlo = Vthi + (size_t)32 * 64 * 2048;
  u16* ctx2 = Vtlo + (size_t)32 * 64 * 2048;  // [4096][2048]
  u16* W2   = ctx2;                           // alias
  u16* Wo2  = Q2;                             // alias
  u16* X2   = (u16*)d_out;                    // alias

  split_kernel<<<4096, 256, 0, stream>>>(x, X2);
  splitw_kernel<<<3072, 256, 0, stream>>>(Wq, Wk, Wv, W2);

  // fused QKV projection: M=4096, N=3072 -> 32x24 = 768 blocks
  gemm3_kernel<<<768, 256, 0, stream>>>(X2, W2, bq, bk, bv,
                                        nullptr, Q2, K2, Vthi, Vtlo, 24, 1);

  attn_kernel<<<dim3(16, 16, 2), 256, 0, stream>>>(Q2, K2, Vthi, Vtlo, ctx2);

  split_kernel<<<1024, 256, 0, stream>>>(Wo, Wo2);

  // output projection: M=4096, N=1024 -> 32x8 = 256 blocks
  gemm3_kernel<<<256, 256, 0, stream>>>(ctx2, Wo2, bo, nullptr, nullptr,
                                        (float*)d_out, nullptr, nullptr, nullptr, nullptr,
                                        8, 0);
}

// Round 10
// 374.362 us; speedup vs baseline: 2.9359x; 1.0468x over previous
//
#include <hip/hip_runtime.h>
#include <math.h>

typedef float v4f __attribute__((ext_vector_type(4)));
typedef __bf16 v8y __attribute__((ext_vector_type(8)));
typedef __attribute__((address_space(1))) const void av1_t;
typedef __attribute__((address_space(3))) void av3_t;
typedef unsigned short u16;

#define SCALE_ 0.125f
#define MASKV_ (-1.0e9f)

// truncation split: x ~= bf(hi) + bf(lo), residual ~2^-16 * |x|
__device__ __forceinline__ u16 bfhi(float f) {
  union { float f; unsigned u; } v; v.f = f;
  return (u16)(v.u >> 16);
}
__device__ __forceinline__ float bf2f(u16 h) {
  union { unsigned u; float f; } v; v.u = ((unsigned)h) << 16;
  return v.f;
}
__device__ __forceinline__ v4f mfma16(v8y a, v8y b, v4f c) {
  return __builtin_amdgcn_mfma_f32_16x16x32_bf16(a, b, c, 0, 0, 0);
}
__device__ __forceinline__ void gload16(const void* g, void* l) {
  __builtin_amdgcn_global_load_lds((av1_t*)g, (av3_t*)l, 16, 0, 0);
}

// ---------------------------------------------------------------------------
// split: src [nrow][1024] f32 -> dst [nrow][2048] bf16 = [hi(1024) | lo(1024)]
// ---------------------------------------------------------------------------
__global__ __launch_bounds__(256) void split_kernel(const float* __restrict__ src,
                                                    u16* __restrict__ dst) {
  const int idx = blockIdx.x * 256 + threadIdx.x;
  const int row = idx >> 8, c4 = idx & 255;
  const float4 v = ((const float4*)src)[idx];
  const u16 h0 = bfhi(v.x), h1 = bfhi(v.y), h2 = bfhi(v.z), h3 = bfhi(v.w);
  ushort4 hi, lo;
  hi.x = h0; hi.y = h1; hi.z = h2; hi.w = h3;
  lo.x = bfhi(v.x - bf2f(h0)); lo.y = bfhi(v.y - bf2f(h1));
  lo.z = bfhi(v.z - bf2f(h2)); lo.w = bfhi(v.w - bf2f(h3));
  *(ushort4*)&dst[(size_t)row * 2048 + c4 * 4] = hi;
  *(ushort4*)&dst[(size_t)row * 2048 + 1024 + c4 * 4] = lo;
}

// fused QKV-weight split: 3072 blocks, one row each
__global__ __launch_bounds__(256) void splitw_kernel(
    const float* __restrict__ Wq, const float* __restrict__ Wk,
    const float* __restrict__ Wv, u16* __restrict__ dst) {
  const int r = blockIdx.x;            // 0..3071
  const int c4 = threadIdx.x;          // 0..255 (float4 chunk)
  const float* src = (r < 1024) ? Wq + (size_t)r * 1024
                   : (r < 2048) ? Wk + (size_t)(r - 1024) * 1024
                                : Wv + (size_t)(r - 2048) * 1024;
  const float4 v = ((const float4*)src)[c4];
  const u16 h0 = bfhi(v.x), h1 = bfhi(v.y), h2 = bfhi(v.z), h3 = bfhi(v.w);
  ushort4 hi, lo;
  hi.x = h0; hi.y = h1; hi.z = h2; hi.w = h3;
  lo.x = bfhi(v.x - bf2f(h0)); lo.y = bfhi(v.y - bf2f(h1));
  lo.z = bfhi(v.z - bf2f(h2)); lo.w = bfhi(v.w - bf2f(h3));
  *(ushort4*)&dst[(size_t)r * 2048 + c4 * 4] = hi;
  *(ushort4*)&dst[(size_t)r * 2048 + 1024 + c4 * 4] = lo;
}

// ---------------------------------------------------------------------------
// Double-buffered 2-phase GEMM (T3 minimum template), hi/lo split, 3 passes
// per subtile (Ahi*Bhi + Alo*Bhi + Ahi*Blo). Tile = (MI*32) x 128, 4 waves.
// Per iteration: issue next subtile's global_load_lds into buf^1 FIRST, then
// ds_read + 3*16(MI/4) MFMA from buf, then ONE barrier (compiler drains
// vmcnt there -> stage latency hidden under compute). LDS = 2 bufs of
// (MI*32*128 + 16K) bytes: quarters Ahi|Alo|Bhi|Blo, +rotate chunk swizzle
// (max 2-way conflict = free), inverse swizzle on global source (G21).
// mode 0: f32 out [M][1024].  mode 1: QKV split-layout writes.
// ---------------------------------------------------------------------------
template<int MI>
__global__ __launch_bounds__(256) void gemm2_kernel(
    const u16* __restrict__ A2, const u16* __restrict__ B2,
    const float* __restrict__ bias0, const float* __restrict__ bias1,
    const float* __restrict__ bias2,
    float* __restrict__ outF,
    u16* __restrict__ Q2, u16* __restrict__ K2,
    u16* __restrict__ Vthi, u16* __restrict__ Vtlo,
    int ntiles_n, int mode)
{
  constexpr int TM = MI * 32;                 // M rows per tile
  constexpr int BUFB = TM * 128 + 16384;      // bytes per buffer
  __shared__ __align__(16) u16 sm[BUFB];      // 2 bufs * BUFB/2 u16 each
  char* smc = (char*)sm;
  const int tid = threadIdx.x;
  const int lane = tid & 63;
  const int wid = tid >> 6;
  const int wm = wid >> 1, wn = wid & 1;
  const int l15 = lane & 15, ck = lane >> 4;

  int bid = blockIdx.x;
  const int cpx = gridDim.x >> 3;             // grid % 8 == 0 -> bijective
  bid = (bid & 7) * cpx + (bid >> 3);
  const int mt = bid / ntiles_n, nt = bid % ntiles_n;
  const int m0 = mt * TM, n0 = nt * 128;

  // fragment LDS byte offsets within a quarter (row stride 64B)
  int offA[MI], offB[4];
  #pragma unroll
  for (int i = 0; i < MI; ++i) {
    const int row = wm * (MI * 16) + i * 16 + l15;
    offA[i] = row * 64 + (((ck + ((row >> 1) & 3)) & 3) * 16);
  }
  #pragma unroll
  for (int j = 0; j < 4; ++j) {
    const int row = wn * 64 + j * 16 + l15;
    offB[j] = row * 64 + (((ck + ((row >> 1) & 3)) & 3) * 16);
  }

  // stage subtile s (K-phys cols [s*32, s*32+32)) into buffer at bufc
  auto STAGE = [&](char* bufc, int s) {
    #pragma unroll
    for (int r = 0; r < MI / 2; ++r) {        // A quarters: TM*4 units
      const int w = r * 256 + tid;
      const int row = w >> 2, cph = w & 3;
      const int clog = (cph - ((row >> 1) & 3)) & 3;
      const size_t ga = (size_t)(m0 + row) * 2048 + s * 32 + clog * 8;
      gload16(&A2[ga], bufc + w * 16);                      // Ahi
      gload16(&A2[ga + 1024], bufc + TM * 64 + w * 16);     // Alo
    }
    #pragma unroll
    for (int r = 0; r < 2; ++r) {             // B quarters: 512 units
      const int w = r * 256 + tid;
      const int row = w >> 2, cph = w & 3;
      const int clog = (cph - ((row >> 1) & 3)) & 3;
      const size_t gb = (size_t)(n0 + row) * 2048 + s * 32 + clog * 8;
      gload16(&B2[gb], bufc + TM * 128 + w * 16);           // Bhi
      gload16(&B2[gb + 1024], bufc + TM * 128 + 8192 + w * 16); // Blo
    }
  };

  v4f acc[MI][4];
  #pragma unroll
  for (int i = 0; i < MI; ++i)
    #pragma unroll
    for (int j = 0; j < 4; ++j) { v4f z = {0.f, 0.f, 0.f, 0.f}; acc[i][j] = z; }

  STAGE(smc, 0);
  __syncthreads();                            // compiler drains vmcnt here
  int cur = 0;

  #pragma unroll 1
  for (int s = 0; s < 32; ++s) {
    char* cb = smc + cur * BUFB;
    if (s < 31) STAGE(smc + (cur ^ 1) * BUFB, s + 1);   // issue early

    v8y bhi[4], af[MI];
    #pragma unroll
    for (int j = 0; j < 4; ++j) bhi[j] = *(const v8y*)(cb + TM * 128 + offB[j]);

    // pass 0: Ahi x Bhi
    #pragma unroll
    for (int i = 0; i < MI; ++i) af[i] = *(const v8y*)(cb + offA[i]);
    #pragma unroll
    for (int j = 0; j < 4; ++j)
      #pragma unroll
      for (int i = 0; i < MI; ++i)
        acc[i][j] = mfma16(af[i], bhi[j], acc[i][j]);

    // pass 1: Alo x Bhi (B frags reused in registers)
    #pragma unroll
    for (int i = 0; i < MI; ++i) af[i] = *(const v8y*)(cb + TM * 64 + offA[i]);
    #pragma unroll
    for (int j = 0; j < 4; ++j)
      #pragma unroll
      for (int i = 0; i < MI; ++i)
        acc[i][j] = mfma16(af[i], bhi[j], acc[i][j]);

    // pass 2: Ahi x Blo
    v8y blo[4];
    #pragma unroll
    for (int j = 0; j < 4; ++j) blo[j] = *(const v8y*)(cb + TM * 128 + 8192 + offB[j]);
    #pragma unroll
    for (int i = 0; i < MI; ++i) af[i] = *(const v8y*)(cb + offA[i]);
    #pragma unroll
    for (int j = 0; j < 4; ++j)
      #pragma unroll
      for (int i = 0; i < MI; ++i)
        acc[i][j] = mfma16(af[i], blo[j], acc[i][j]);

    __syncthreads();   // publishes buf^1 stages; readers of buf done
    cur ^= 1;
  }

  // epilogue. D layout: col = lane&15, row = (lane>>4)*4 + r
  #pragma unroll
  for (int i = 0; i < MI; ++i) {
    #pragma unroll
    for (int j = 0; j < 4; ++j) {
      #pragma unroll
      for (int r = 0; r < 4; ++r) {
        const int m = m0 + wm * (MI * 16) + i * 16 + (lane >> 4) * 4 + r;
        const int n = n0 + wn * 64 + j * 16 + (lane & 15);
        float y = acc[i][j][r];
        if (mode == 0) {
          outF[(size_t)m * 1024 + n] = y + bias0[n];
        } else {
          const int which = n >> 10;
          const int nn = n & 1023;
          const int hh = nn >> 6, dk = n & 63;
          const int b = m >> 11, sr = m & 2047;
          y += (which == 0 ? bias0[nn] : (which == 1 ? bias1[nn] : bias2[nn]));
          const u16 hi = bfhi(y);
          const u16 lo = bfhi(y - bf2f(hi));
          const size_t bh = (size_t)(b * 16 + hh);
          if (which == 2) {         // V stored transposed: [bh][dk][s]
            const size_t a = (bh * 64 + dk) * 2048 + sr;
            Vthi[a] = hi; Vtlo[a] = lo;
          } else {                  // Q/K: [bh][s][128] = [hi(64)|lo(64)]
            u16* dst = (which == 0) ? Q2 : K2;
            const size_t a = (bh * 2048 + sr) * 128 + dk;
            dst[a] = hi; dst[a + 64] = lo;
          }
        }
      }
    }
  }
}

// ---------------------------------------------------------------------------
// Flash attention, bf16-split MFMA (unchanged from passing R3/R4/R5).
// ---------------------------------------------------------------------------
__global__ __launch_bounds__(256) void attn_kernel(
    const u16* __restrict__ Q2, const u16* __restrict__ K2,
    const u16* __restrict__ Vthi, const u16* __restrict__ Vtlo,
    u16* __restrict__ ctx2)
{
  __shared__ __align__(16) u16 sm[24576];   // 49152 bytes
  const int tid = threadIdx.x, lane = tid & 63, wid = tid >> 6;
  const int h = blockIdx.y, b = blockIdx.z;
  const size_t bh = (size_t)(b * 16 + h);
  const u16* Qb = Q2 + bh * 2048 * 128;
  const u16* Kb = K2 + bh * 2048 * 128;
  const u16* Vhb = Vthi + bh * (size_t)64 * 2048;
  const u16* Vlb = Vtlo + bh * (size_t)64 * 2048;

  #pragma unroll 1
  for (int half = 0; half < 2; ++half) {
    const int qt = (half == 0) ? (int)blockIdx.x : 31 - (int)blockIdx.x;
    const int q0 = qt * 64;

    v8y qf[4];
    #pragma unroll
    for (int pc = 0; pc < 4; ++pc)
      qf[pc] = *(const v8y*)&Qb[(size_t)(q0 + wid * 16 + (lane & 15)) * 128
                                + pc * 32 + (lane >> 4) * 8];

    v4f o[4];
    float mrun[4], lrun[4];
    #pragma unroll
    for (int nb = 0; nb < 4; ++nb) { v4f z = {0.f,0.f,0.f,0.f}; o[nb] = z; }
    #pragma unroll
    for (int r = 0; r < 4; ++r) { mrun[r] = -INFINITY; lrun[r] = 0.f; }

    for (int kb = 0; kb <= qt; ++kb) {
      const int k0 = kb * 64;
      __syncthreads();
      #pragma unroll
      for (int p = 0; p < 4; ++p) {
        const int u = p * 256 + tid;
        const int row = u >> 4, c = u & 15;
        const int cph = c ^ (row & 7);
        const uint4 kv = *(const uint4*)&Kb[(size_t)(k0 + row) * 128 + c * 8];
        *(uint4*)((char*)sm + row * 256 + cph * 16) = kv;
        const uint4 vv = (c < 8)
            ? *(const uint4*)&Vhb[(size_t)row * 2048 + k0 + c * 8]
            : *(const uint4*)&Vlb[(size_t)row * 2048 + k0 + (c - 8) * 8];
        *(uint4*)((char*)sm + 16384 + row * 256 + cph * 16) = vv;
      }
      __syncthreads();

      v4f s[4];
      #pragma unroll
      for (int nb = 0; nb < 4; ++nb) { v4f z = {0.f,0.f,0.f,0.f}; s[nb] = z; }
      #pragma unroll
      for (int kc = 0; kc < 6; ++kc) {
        const int ma = (kc < 2) ? kc : kc - 2;
        const int mb = (kc < 4) ? kc : kc - 4;
        #pragma unroll
        for (int nb = 0; nb < 4; ++nb) {
          const int row = nb * 16 + (lane & 15);
          const int ch = (mb * 4 + (lane >> 4)) ^ (row & 7);
          const v8y kf = *(const v8y*)((const char*)sm + row * 256 + ch * 16);
          s[nb] = mfma16(qf[ma], kf, s[nb]);
        }
      }

      const bool domask = (kb == qt);
      float alpha[4];
      char* pbase = (char*)sm + 32768 + wid * 4096;
      #pragma unroll
      for (int r = 0; r < 4; ++r) {
        float sv[4];
        #pragma unroll
        for (int nb = 0; nb < 4; ++nb) {
          float v = s[nb][r] * SCALE_;
          if (domask) {
            const int qg = q0 + wid * 16 + (lane >> 4) * 4 + r;
            const int kg = k0 + nb * 16 + (lane & 15);
            if (kg > qg) v = MASKV_;
          }
          sv[nb] = v;
        }
        float rm = fmaxf(fmaxf(sv[0], sv[1]), fmaxf(sv[2], sv[3]));
        rm = fmaxf(rm, __shfl_xor(rm, 1));
        rm = fmaxf(rm, __shfl_xor(rm, 2));
        rm = fmaxf(rm, __shfl_xor(rm, 4));
        rm = fmaxf(rm, __shfl_xor(rm, 8));
        const float mnew = fmaxf(mrun[r], rm);
        const float al = __expf(mrun[r] - mnew);
        const int pr = (lane >> 4) * 4 + r;
        char* prow = pbase + pr * 256;
        float ls = 0.f;
        #pragma unroll
        for (int nb = 0; nb < 4; ++nb) {
          const float pv = __expf(sv[nb] - mnew);
          ls += pv;
          const u16 phi = bfhi(pv);
          const u16 plo = bfhi(pv - bf2f(phi));
          const int kp = nb * 16 + (lane & 15);
          *(u16*)(prow + (((kp >> 3)       ^ (pr & 7)) * 16) + (kp & 7) * 2) = phi;
          *(u16*)(prow + (((8 + (kp >> 3)) ^ (pr & 7)) * 16) + (kp & 7) * 2) = plo;
        }
        ls += __shfl_xor(ls, 1);
        ls += __shfl_xor(ls, 2);
        ls += __shfl_xor(ls, 4);
        ls += __shfl_xor(ls, 8);
        lrun[r] = lrun[r] * al + ls;
        mrun[r] = mnew;
        alpha[r] = al;
      }
      #pragma unroll
      for (int nb = 0; nb < 4; ++nb)
        #pragma unroll
        for (int r = 0; r < 4; ++r)
          o[nb][r] *= alpha[r];

      #pragma unroll
      for (int kc = 0; kc < 6; ++kc) {
        const int ma = (kc < 2) ? kc : kc - 2;
        const int mb = (kc < 4) ? kc : kc - 4;
        const int prow_r = lane & 15;
        const int pch = (ma * 4 + (lane >> 4)) ^ (prow_r & 7);
        const v8y pf = *(const v8y*)(pbase + prow_r * 256 + pch * 16);
        #pragma unroll
        for (int nb = 0; nb < 4; ++nb) {
          const int row = nb * 16 + (lane & 15);
          const int ch = (mb * 4 + (lane >> 4)) ^ (row & 7);
          const v8y vf = *(const v8y*)((const char*)sm + 16384 + row * 256 + ch * 16);
          o[nb] = mfma16(pf, vf, o[nb]);
        }
      }
    }

    #pragma unroll
    for (int r = 0; r < 4; ++r) {
      const float inv = 1.0f / (lrun[r] + 1e-8f);
      const int q = q0 + wid * 16 + (lane >> 4) * 4 + r;
      const size_t mrow = (size_t)(b * 2048 + q) * 2048;
      #pragma unroll
      for (int nb = 0; nb < 4; ++nb) {
        const float y = o[nb][r] * inv;
        const u16 hi = bfhi(y);
        const u16 lo = bfhi(y - bf2f(hi));
        const int col = h * 64 + nb * 16 + (lane & 15);
        ctx2[mrow + col] = hi;
        ctx2[mrow + 1024 + col] = lo;
      }
    }
  }
}

// ---------------------------------------------------------------------------
// Workspace plan (exactly 67,108,864 B):
//   ws: Q2(16.8M) K2(16.8M) Vthi(8.4M) Vtlo(8.4M) ctx2(16.8M)
//   W2 aliases ctx2; Wo2 aliases Q2 (split after attn); X2 lives in d_out.
// ---------------------------------------------------------------------------
extern "C" void kernel_launch(void* const* d_in, const int* in_sizes, int n_in,
                              void* d_out, int out_size, void* d_ws, size_t ws_size,
                              hipStream_t stream)
{
  const float* x  = (const float*)d_in[0];
  const float* Wq = (const float*)d_in[1];
  const float* bq = (const float*)d_in[2];
  const float* Wk = (const float*)d_in[3];
  const float* bk = (const float*)d_in[4];
  const float* Wv = (const float*)d_in[5];
  const float* bv = (const float*)d_in[6];
  const float* Wo = (const float*)d_in[7];
  const float* bo = (const float*)d_in[8];
  // d_in[9] = causal mask; implemented analytically.

  u16* wsp  = (u16*)d_ws;
  u16* Q2   = wsp;                            // [32][2048][128]
  u16* K2   = Q2 + (size_t)32 * 2048 * 128;
  u16* Vthi = K2 + (size_t)32 * 2048 * 128;   // [32][64][2048]
  u16* Vtlo = Vthi + (size_t)32 * 64 * 2048;
  u16* ctx2 = Vtlo + (size_t)32 * 64 * 2048;  // [4096][2048]
  u16* W2   = ctx2;                           // alias
  u16* Wo2  = Q2;                             // alias
  u16* X2   = (u16*)d_out;                    // alias

  split_kernel<<<4096, 256, 0, stream>>>(x, X2);
  splitw_kernel<<<3072, 256, 0, stream>>>(Wq, Wk, Wv, W2);

  // fused QKV projection: M=4096 (tile 128), N=3072 -> 32x24 = 768 blocks
  gemm2_kernel<4><<<768, 256, 0, stream>>>(X2, W2, bq, bk, bv,
                                           nullptr, Q2, K2, Vthi, Vtlo, 24, 1);

  attn_kernel<<<dim3(16, 16, 2), 256, 0, stream>>>(Q2, K2, Vthi, Vtlo, ctx2);

  split_kernel<<<1024, 256, 0, stream>>>(Wo, Wo2);

  // output projection: M=4096 (tile 64), N=1024 -> 64x8 = 512 blocks
  gemm2_kernel<2><<<512, 256, 0, stream>>>(ctx2, Wo2, bo, nullptr, nullptr,
                                           (float*)d_out, nullptr, nullptr, nullptr, nullptr,
                                           8, 0);
}